// Round 1
// baseline (297.958 us; speedup 1.0000x reference)
//
#include <hip/hip_runtime.h>
#include <math.h>

// SymmetryLoss: 3 plane reflections + 3 quaternion rotations of 1e6 points,
// nearest-grid-point distance (256^3x3 grid gather), plus tiny 3x3 regularizer.
// Memory-bound on the random 12B gathers into the 201MB grid.

#define RGRID 256

__device__ __forceinline__ float grid_dist(float tx, float ty, float tz,
                                           const float* __restrict__ grid,
                                           float g0, float g1, float g2,
                                           float s0, float s1, float s2) {
    // idx = clip(round((tp - gmin)/(gmax-gmin) * (R-1)), 0, R-1)
    float f0 = rintf((tx - g0) * s0);   // rintf = round-half-to-even, matches jnp.round
    float f1 = rintf((ty - g1) * s1);
    float f2 = rintf((tz - g2) * s2);
    f0 = fminf(fmaxf(f0, 0.0f), 255.0f);
    f1 = fminf(fmaxf(f1, 0.0f), 255.0f);
    f2 = fminf(fmaxf(f2, 0.0f), 255.0f);
    int i0 = (int)f0, i1 = (int)f1, i2 = (int)f2;
    int base = ((i0 * RGRID + i1) * RGRID + i2) * 3;   // < 2^31, fits int
    float cx = grid[base + 0];
    float cy = grid[base + 1];
    float cz = grid[base + 2];
    float dx = tx - cx, dy = ty - cy, dz = tz - cz;
    return sqrtf(fmaf(dx, dx, fmaf(dy, dy, dz * dz)));
}

__global__ void __launch_bounds__(256)
symloss_main(const float* __restrict__ planes, const float* __restrict__ axes,
             const float* __restrict__ pts, const float* __restrict__ grid,
             const float* __restrict__ gmin, const float* __restrict__ gmax,
             float* __restrict__ acc, int N) {
    // Broadcast parameters (uniform addresses -> scalar/L1 cached loads)
    float P[12], Q[12];
#pragma unroll
    for (int i = 0; i < 12; ++i) { P[i] = planes[i]; Q[i] = axes[i]; }
    float g0 = gmin[0], g1 = gmin[1], g2 = gmin[2];
    float s0 = 255.0f / (gmax[0] - g0);
    float s1 = 255.0f / (gmax[1] - g1);
    float s2 = 255.0f / (gmax[2] - g2);

    int idx = blockIdx.x * blockDim.x + threadIdx.x;
    float lsum = 0.0f;
    if (idx < N) {
        float px = pts[3 * idx + 0];
        float py = pts[3 * idx + 1];
        float pz = pts[3 * idx + 2];

        float tpx[6], tpy[6], tpz[6];
        // 3 plane reflections: tp = p - 2*(p.n + d)*n
#pragma unroll
        for (int k = 0; k < 3; ++k) {
            float nx = P[4 * k + 0], ny = P[4 * k + 1], nz = P[4 * k + 2], d = P[4 * k + 3];
            float proj = px * nx + py * ny + pz * nz + d;
            float m2p = -2.0f * proj;
            tpx[k] = fmaf(m2p, nx, px);
            tpy[k] = fmaf(m2p, ny, py);
            tpz[k] = fmaf(m2p, nz, pz);
        }
        // 3 quaternion conjugations: o = (q * (0,p) * q_conj)[1:]
#pragma unroll
        for (int k = 0; k < 3; ++k) {
            float qw = Q[4 * k + 0], qx = Q[4 * k + 1], qy = Q[4 * k + 2], qz = Q[4 * k + 3];
            float rw = -(qx * px + qy * py + qz * pz);
            float rx = qw * px + qy * pz - qz * py;
            float ry = qw * py - qx * pz + qz * px;
            float rz = qw * pz + qx * py - qy * px;
            tpx[3 + k] = -rw * qx + rx * qw - ry * qz + rz * qy;
            tpy[3 + k] = -rw * qy + rx * qz + ry * qw - rz * qx;
            tpz[3 + k] = -rw * qz - rx * qy + ry * qx + rz * qw;
        }
        // 6 independent gathers -> compiler keeps all in flight
#pragma unroll
        for (int k = 0; k < 6; ++k) {
            lsum += grid_dist(tpx[k], tpy[k], tpz[k], grid, g0, g1, g2, s0, s1, s2);
        }
    }

    // wave(64) shuffle reduce
#pragma unroll
    for (int off = 32; off > 0; off >>= 1)
        lsum += __shfl_down(lsum, off, 64);
    __shared__ float wsum[4];
    int lane = threadIdx.x & 63;
    int wid  = threadIdx.x >> 6;
    if (lane == 0) wsum[wid] = lsum;
    __syncthreads();
    if (threadIdx.x == 0) {
        atomicAdd(acc, wsum[0] + wsum[1] + wsum[2] + wsum[3]);
    }
}

__global__ void symloss_final(const float* __restrict__ planes,
                              const float* __restrict__ axes,
                              const float* __restrict__ acc,
                              float* __restrict__ out, float invN) {
    // single thread: tiny 3x3 work
    float sd = acc[0] * invN;

    float n[3][3];
#pragma unroll
    for (int i = 0; i < 3; ++i)
#pragma unroll
        for (int j = 0; j < 3; ++j) n[i][j] = planes[4 * i + j];

    float sA = 0.0f;
#pragma unroll
    for (int i = 0; i < 3; ++i)
#pragma unroll
        for (int j = 0; j < 3; ++j) {
            float a = n[i][0] * n[j][0] + n[i][1] * n[j][1] + n[i][2] * n[j][2]
                      - (i == j ? 1.0f : 0.0f);
            sA += a * a;
        }

    float v[3][3];
#pragma unroll
    for (int i = 0; i < 3; ++i) {
        float vx = axes[4 * i + 1], vy = axes[4 * i + 2], vz = axes[4 * i + 3];
        float nrm = sqrtf(vx * vx + vy * vy + vz * vz);
        nrm = fmaxf(nrm, 1e-12f);
        v[i][0] = vx / nrm; v[i][1] = vy / nrm; v[i][2] = vz / nrm;
    }
    float sB = 0.0f;
#pragma unroll
    for (int i = 0; i < 3; ++i)
#pragma unroll
        for (int j = 0; j < 3; ++j) {
            float b = v[i][0] * v[j][0] + v[i][1] * v[j][1] + v[i][2] * v[j][2]
                      - (i == j ? 1.0f : 0.0f);
            sB += b * b;
        }

    float r = sA + sB;
    out[0] = sd + 25.0f * r;   // final_loss
    out[1] = sd;               // total_loss_sd
    out[2] = r;                // total_loss_r
}

extern "C" void kernel_launch(void* const* d_in, const int* in_sizes, int n_in,
                              void* d_out, int out_size, void* d_ws, size_t ws_size,
                              hipStream_t stream) {
    const float* planes = (const float*)d_in[0];   // (1,3,4)
    const float* axes   = (const float*)d_in[1];   // (1,3,4)
    const float* pts    = (const float*)d_in[2];   // (N,3)
    const float* grid   = (const float*)d_in[3];   // (256,256,256,3)
    const float* gmin   = (const float*)d_in[4];   // (3,)
    const float* gmax   = (const float*)d_in[5];   // (3,)
    float* out = (float*)d_out;
    float* acc = (float*)d_ws;

    int N = in_sizes[2] / 3;

    hipMemsetAsync(acc, 0, sizeof(float), stream);

    int blocks = (N + 255) / 256;
    hipLaunchKernelGGL(symloss_main, dim3(blocks), dim3(256), 0, stream,
                       planes, axes, pts, grid, gmin, gmax, acc, N);
    hipLaunchKernelGGL(symloss_final, dim3(1), dim3(1), 0, stream,
                       planes, axes, acc, out, 1.0f / (float)N);
}

// Round 2
// 266.411 us; speedup vs baseline: 1.1184x; 1.1184x over previous
//
#include <hip/hip_runtime.h>
#include <math.h>

// SymmetryLoss: 3 plane reflections + 3 quaternion rotations of 1e6 points,
// nearest-grid-point distance (256^3x3 grid gather), plus tiny 3x3 regularizer.
// Scatter-latency bound on the random 12B gathers into the 201MB grid.
// R2: 4 points/thread, float4 point loads, 24 outstanding gathers/thread.

#define RGRID 256
#define PTS_PER_THREAD 4

__global__ void __launch_bounds__(256)
symloss_main(const float* __restrict__ planes, const float* __restrict__ axes,
             const float* __restrict__ pts, const float* __restrict__ grid,
             const float* __restrict__ gmin, const float* __restrict__ gmax,
             float* __restrict__ acc, int N) {
    // Uniform-address parameter loads -> scalar registers
    float P[12], Q[12];
#pragma unroll
    for (int i = 0; i < 12; ++i) { P[i] = planes[i]; Q[i] = axes[i]; }
    const float g0 = gmin[0], g1 = gmin[1], g2 = gmin[2];
    const float s0 = 255.0f / (gmax[0] - g0);
    const float s1 = 255.0f / (gmax[1] - g1);
    const float s2 = 255.0f / (gmax[2] - g2);

    const int t  = blockIdx.x * blockDim.x + threadIdx.x;
    const int p0 = t * PTS_PER_THREAD;

    float lsum = 0.0f;
    if (p0 < N) {
        float px[4], py[4], pz[4];
        int npts;
        if (p0 + 3 < N) {
            // 4 points = 12 floats = 3 aligned float4 loads
            const float4* pts4 = (const float4*)pts;
            float4 a = pts4[3 * t + 0];
            float4 b = pts4[3 * t + 1];
            float4 c = pts4[3 * t + 2];
            px[0] = a.x; py[0] = a.y; pz[0] = a.z;
            px[1] = a.w; py[1] = b.x; pz[1] = b.y;
            px[2] = b.z; py[2] = b.w; pz[2] = c.x;
            px[3] = c.y; py[3] = c.z; pz[3] = c.w;
            npts = 4;
        } else {
            npts = N - p0;
#pragma unroll
            for (int i = 0; i < 4; ++i) {
                int p = p0 + (i < npts ? i : 0);   // clamp: duplicates are masked below
                px[i] = pts[3 * p + 0];
                py[i] = pts[3 * p + 1];
                pz[i] = pts[3 * p + 2];
            }
        }

        // 24 transformed points
        float tx[24], ty[24], tz[24];
#pragma unroll
        for (int i = 0; i < 4; ++i) {
            // 3 plane reflections: tp = p - 2*(p.n + d)*n
#pragma unroll
            for (int k = 0; k < 3; ++k) {
                float nx = P[4 * k + 0], ny = P[4 * k + 1], nz = P[4 * k + 2], d = P[4 * k + 3];
                float proj = px[i] * nx + py[i] * ny + pz[i] * nz + d;
                float m2p = -2.0f * proj;
                int o = i * 6 + k;
                tx[o] = fmaf(m2p, nx, px[i]);
                ty[o] = fmaf(m2p, ny, py[i]);
                tz[o] = fmaf(m2p, nz, pz[i]);
            }
            // 3 quaternion conjugations: o = (q * (0,p) * q_conj)[1:]
#pragma unroll
            for (int k = 0; k < 3; ++k) {
                float qw = Q[4 * k + 0], qx = Q[4 * k + 1], qy = Q[4 * k + 2], qz = Q[4 * k + 3];
                float rw = -(qx * px[i] + qy * py[i] + qz * pz[i]);
                float rx = qw * px[i] + qy * pz[i] - qz * py[i];
                float ry = qw * py[i] - qx * pz[i] + qz * px[i];
                float rz = qw * pz[i] + qx * py[i] - qy * px[i];
                int o = i * 6 + 3 + k;
                tx[o] = -rw * qx + rx * qw - ry * qz + rz * qy;
                ty[o] = -rw * qy + rx * qz + ry * qw - rz * qx;
                tz[o] = -rw * qz - rx * qy + ry * qx + rz * qw;
            }
        }

        // 24 independent gathers; compute all addresses first so the compiler
        // can batch-issue the loads.
        int base[24];
#pragma unroll
        for (int o = 0; o < 24; ++o) {
            float f0 = rintf((tx[o] - g0) * s0);  // round-half-to-even == jnp.round
            float f1 = rintf((ty[o] - g1) * s1);
            float f2 = rintf((tz[o] - g2) * s2);
            f0 = fminf(fmaxf(f0, 0.0f), 255.0f);
            f1 = fminf(fmaxf(f1, 0.0f), 255.0f);
            f2 = fminf(fmaxf(f2, 0.0f), 255.0f);
            int i0 = (int)f0, i1 = (int)f1, i2 = (int)f2;
            base[o] = ((i0 * RGRID + i1) * RGRID + i2) * 3;
        }
        float partial[4] = {0.0f, 0.0f, 0.0f, 0.0f};
#pragma unroll
        for (int o = 0; o < 24; ++o) {
            float cx = grid[base[o] + 0];
            float cy = grid[base[o] + 1];
            float cz = grid[base[o] + 2];
            float dx = tx[o] - cx, dy = ty[o] - cy, dz = tz[o] - cz;
            partial[o / 6] += sqrtf(fmaf(dx, dx, fmaf(dy, dy, dz * dz)));
        }
#pragma unroll
        for (int i = 0; i < 4; ++i)
            if (i < npts) lsum += partial[i];
    }

    // wave(64) shuffle reduce -> LDS -> one atomic per block
#pragma unroll
    for (int off = 32; off > 0; off >>= 1)
        lsum += __shfl_down(lsum, off, 64);
    __shared__ float wsum[4];
    int lane = threadIdx.x & 63;
    int wid  = threadIdx.x >> 6;
    if (lane == 0) wsum[wid] = lsum;
    __syncthreads();
    if (threadIdx.x == 0) {
        atomicAdd(acc, wsum[0] + wsum[1] + wsum[2] + wsum[3]);
    }
}

__global__ void symloss_final(const float* __restrict__ planes,
                              const float* __restrict__ axes,
                              const float* __restrict__ acc,
                              float* __restrict__ out, float invN) {
    float sd = acc[0] * invN;

    float n[3][3];
#pragma unroll
    for (int i = 0; i < 3; ++i)
#pragma unroll
        for (int j = 0; j < 3; ++j) n[i][j] = planes[4 * i + j];

    float sA = 0.0f;
#pragma unroll
    for (int i = 0; i < 3; ++i)
#pragma unroll
        for (int j = 0; j < 3; ++j) {
            float a = n[i][0] * n[j][0] + n[i][1] * n[j][1] + n[i][2] * n[j][2]
                      - (i == j ? 1.0f : 0.0f);
            sA += a * a;
        }

    float v[3][3];
#pragma unroll
    for (int i = 0; i < 3; ++i) {
        float vx = axes[4 * i + 1], vy = axes[4 * i + 2], vz = axes[4 * i + 3];
        float nrm = sqrtf(vx * vx + vy * vy + vz * vz);
        nrm = fmaxf(nrm, 1e-12f);
        v[i][0] = vx / nrm; v[i][1] = vy / nrm; v[i][2] = vz / nrm;
    }
    float sB = 0.0f;
#pragma unroll
    for (int i = 0; i < 3; ++i)
#pragma unroll
        for (int j = 0; j < 3; ++j) {
            float b = v[i][0] * v[j][0] + v[i][1] * v[j][1] + v[i][2] * v[j][2]
                      - (i == j ? 1.0f : 0.0f);
            sB += b * b;
        }

    float r = sA + sB;
    out[0] = sd + 25.0f * r;   // final_loss
    out[1] = sd;               // total_loss_sd
    out[2] = r;                // total_loss_r
}

extern "C" void kernel_launch(void* const* d_in, const int* in_sizes, int n_in,
                              void* d_out, int out_size, void* d_ws, size_t ws_size,
                              hipStream_t stream) {
    const float* planes = (const float*)d_in[0];   // (1,3,4)
    const float* axes   = (const float*)d_in[1];   // (1,3,4)
    const float* pts    = (const float*)d_in[2];   // (N,3)
    const float* grid   = (const float*)d_in[3];   // (256,256,256,3)
    const float* gmin   = (const float*)d_in[4];   // (3,)
    const float* gmax   = (const float*)d_in[5];   // (3,)
    float* out = (float*)d_out;
    float* acc = (float*)d_ws;

    int N = in_sizes[2] / 3;

    hipMemsetAsync(acc, 0, sizeof(float), stream);

    int nthreads = (N + PTS_PER_THREAD - 1) / PTS_PER_THREAD;
    int blocks = (nthreads + 255) / 256;
    hipLaunchKernelGGL(symloss_main, dim3(blocks), dim3(256), 0, stream,
                       planes, axes, pts, grid, gmin, gmax, acc, N);
    hipLaunchKernelGGL(symloss_final, dim3(1), dim3(1), 0, stream,
                       planes, axes, acc, out, 1.0f / (float)N);
}